// Round 7
// baseline (148.486 us; speedup 1.0000x reference)
//
#include <hip/hip_runtime.h>

#define NUM_GRAPHS 512
#define NPG 200      // nodes per graph
#define EPG 3200     // edges per graph
#define NROIS 200    // input feature dim
#define HID 64
#define OUTC 2
#define APITCH 232   // adjacency row pitch (bytes) in fallback kernel
#define NPITCH 26    // v10 adjacency nibble-row pitch in DWORDS (208 nibbles)
#define HPITCH 232   // hpTl row pitch (elements); 464 B
#define WIMG_ELEMS (7 * 4 * 2 * 64 * 8)   // 28672 ushorts (W hi/lo frag image)
#define WS_NEEDED ((size_t)WIMG_ELEMS * 2)

typedef short v8s __attribute__((ext_vector_type(8)));
typedef float v4f __attribute__((ext_vector_type(4)));

__device__ __forceinline__ unsigned bf16_rne(float f) {
  unsigned u = __float_as_uint(f);
  return (u + 0x7fffu + ((u >> 16) & 1u)) >> 16;
}

// ============ prep: W -> bf16 hi/lo fragment-order image ============
__global__ void prep_wimg(const float* __restrict__ cw, unsigned short* __restrict__ wimg) {
  int idx = blockIdx.x * 256 + threadIdx.x;
  if (idx >= WIMG_ELEMS) return;
  int i    = idx & 7;
  int lane = (idx >> 3) & 63;
  int hl   = (idx >> 9) & 1;
  int nt   = (idx >> 10) & 3;
  int kt   = idx >> 12;
  int k  = kt * 32 + (lane >> 4) * 8 + i;
  int ch = nt * 16 + (lane & 15);
  float f = (k < NROIS) ? cw[k * HID + ch] : 0.f;
  unsigned hi = bf16_rne(f);
  float lo = f - __uint_as_float(hi << 16);
  wimg[idx] = hl ? (unsigned short)(__float_as_uint(lo) >> 16) : (unsigned short)hi;
}

// ============ fused kernel v10 ============
// vs v8: W image (56KB) staged into LDS ONCE -> GEMM1 has ZERO in-loop barriers;
// waves free-run with a 3-slot x prefetch ring (depth 3), de-phasing the chip-wide
// memory bursts that barrier-lockstep created. Paid for by 4-bit adjacency counts
// (20.8KB; max cell multiplicity << 15 for 3200 rand edges over 200x200 + diag).
// Numerics identical to v8 (same values, same MFMA order, counts exact in bf16).
// LDS: 20800 (adjN) + 57344 (W image | hpTl union) + 800 + 800 + 256
//    = 80000 B -> 2 blocks/CU (16 waves).
struct __align__(16) Smem3 {
  unsigned int adjN[200 * NPITCH];        // 4-bit (A+I) counts, 208 nibbles/row
  union {
    unsigned short wl[WIMG_ELEMS];        // full W hi/lo image (GEMM1)
    unsigned short hpTl[HID * HPITCH];    // bf16 dinv[src]*h[src][ch] (post-GEMM1)
  } u;
  int cnt[NPG];                           // in-degree (edges only; +1 for self-loop)
  float dinv[NPG];
  int pool[HID];
};

__device__ __forceinline__ v8s tobf16(const float4& a, const float4& b) {
  v8s r;
  r[0] = (short)bf16_rne(a.x); r[1] = (short)bf16_rne(a.y);
  r[2] = (short)bf16_rne(a.z); r[3] = (short)bf16_rne(a.w);
  r[4] = (short)bf16_rne(b.x); r[5] = (short)bf16_rne(b.y);
  r[6] = (short)bf16_rne(b.z); r[7] = (short)bf16_rne(b.w);
  return r;
}

// x fragment loads for K-tile kt: lane reads 8 consecutive floats
// x[node][kt*32 + q*8 ..). kt=6,q>=1 runs past col 200 -> zero-fill.
__device__ __forceinline__ void xfetch(const float* __restrict__ x, int base,
                                       int kt, int q, const int* mts, const int* nrow,
                                       float4 xa[2][2]) {
  const int k0 = kt * 32 + q * 8;
  const bool ok = (k0 + 8 <= NROIS);
  #pragma unroll
  for (int mi = 0; mi < 2; ++mi) {
    if (mts[mi] >= 0) {
      if (ok) {
        const float* px = x + (size_t)(base + nrow[mi]) * NROIS + k0;
        xa[mi][0] = *(const float4*)px;
        xa[mi][1] = *(const float4*)(px + 4);
      } else {
        xa[mi][0] = make_float4(0.f, 0.f, 0.f, 0.f);
        xa[mi][1] = make_float4(0.f, 0.f, 0.f, 0.f);
      }
    }
  }
}

// one kt of GEMM1: convert x slot, issue this slot's next prefetch (kt+3),
// read W fragments from LDS, 16 MFMAs. All indices compile-time static.
template<int KT>
__device__ __forceinline__ void kt1(const float* __restrict__ x, int base, int q,
                                    const int* mts, const int* nrow,
                                    const unsigned short* wl,
                                    float4 (&slot)[2][2], v4f (&acc)[2][4], int lane) {
  v8s xh2[2];
  #pragma unroll
  for (int mi = 0; mi < 2; ++mi)
    if (mts[mi] >= 0) xh2[mi] = tobf16(slot[mi][0], slot[mi][1]);
  if constexpr (KT + 3 <= 6)
    xfetch(x, base, KT + 3, q, mts, nrow, slot);   // ring refill, 3 kt of slack
  v8s whi[4], wlo[4];
  #pragma unroll
  for (int nt = 0; nt < 4; ++nt) {
    const unsigned short* pw = wl + (size_t)(((KT * 4 + nt) * 2) * 64 + lane) * 8;
    whi[nt] = *(const v8s*)pw;
    wlo[nt] = *(const v8s*)(pw + 64 * 8);
  }
  #pragma unroll
  for (int mi = 0; mi < 2; ++mi) {
    if (mts[mi] >= 0) {
      #pragma unroll
      for (int nt = 0; nt < 4; ++nt) {
        acc[mi][nt] = __builtin_amdgcn_mfma_f32_16x16x32_bf16(wlo[nt], xh2[mi], acc[mi][nt], 0, 0, 0);
        acc[mi][nt] = __builtin_amdgcn_mfma_f32_16x16x32_bf16(whi[nt], xh2[mi], acc[mi][nt], 0, 0, 0);
      }
    }
  }
}

__global__ __launch_bounds__(512, 4)
void gcn_fused10(const float* __restrict__ x,
                 const int* __restrict__ ei,
                 const unsigned short* __restrict__ wimg,
                 const float* __restrict__ cb,
                 const float* __restrict__ lw,
                 const float* __restrict__ lb,
                 float* __restrict__ out,
                 int Etot) {
  __shared__ Smem3 s;
  const int g = blockIdx.x;
  const int tid = threadIdx.x;
  const int base = g * NPG;
  const int ebase = g * EPG;
  const int lane = tid & 63;
  const int w = __builtin_amdgcn_readfirstlane(tid >> 6);  // 0..7
  const int ml = tid & 15;
  const int q  = (tid >> 4) & 3;

  int mts[2];
  mts[0] = w;
  mts[1] = (w < 5) ? 8 + w : -1;
  int nrow[2];                       // clamped row index for x loads (junk discarded)
  #pragma unroll
  for (int mi = 0; mi < 2; ++mi) {
    int node = mts[mi] * 16 + ml;
    nrow[mi] = (node < NPG) ? node : 0;
  }

  // ---- startup: x tiles 0-2 into ring, FULL W image DMA, edge loads; zero LDS ----
  float4 xa[3][2][2];
  xfetch(x, base, 0, q, mts, nrow, xa[0]);
  xfetch(x, base, 1, q, mts, nrow, xa[1]);
  xfetch(x, base, 2, q, mts, nrow, xa[2]);
  #pragma unroll
  for (int c = 0; c < 7; ++c) {        // 7 x 8KB = whole wimg; wave w owns +w*1024
    const char* gp = (const char*)wimg + c * 8192 + (size_t)(w * 64 + lane) * 16;
    unsigned char* lp = (unsigned char*)s.u.wl + c * 8192 + w * 1024;
    __builtin_amdgcn_global_load_lds(
        (const __attribute__((address_space(1))) unsigned int*)gp,
        (__attribute__((address_space(3))) unsigned int*)lp, 16, 0, 0);
  }
  int esrc[7], edst[7];
  #pragma unroll
  for (int r = 0; r < 7; ++r) {
    int e = tid + r * 512;
    esrc[r] = -1; edst[r] = 0;
    if (e < EPG) {
      esrc[r] = ei[ebase + e] - base;
      edst[r] = ei[Etot + ebase + e] - base;
    }
  }
  {
    uint4* z = (uint4*)s.adjN;
    const uint4 z4 = {0u, 0u, 0u, 0u};
    #pragma unroll
    for (int i = 0; i < 3; ++i) {
      int idx = tid + i * 512;
      if (idx < (200 * NPITCH) / 4) z[idx] = z4;
    }
    if (tid < NPG) s.cnt[tid] = 0;
    if (tid < HID) s.pool[tid] = 0;   // relu >= 0 -> 0 is identity for max
  }
  __syncthreads();   // zeroes visible; W DMA + x0-2 + edges drained (full drain)

  // ---- scatter (A+I) 4-bit counts + in-degree (fire-and-forget ds atomics;
  //      they drain at the post-GEMM1 barrier, long before adjN/cnt are read) ----
  {
    #pragma unroll
    for (int r = 0; r < 7; ++r) {
      if (esrc[r] >= 0) {
        int idx = edst[r] * 208 + esrc[r];          // nibble index
        atomicAdd(&s.adjN[idx >> 3], 1u << ((idx & 7) * 4));
        atomicAdd(&s.cnt[edst[r]], 1);
      }
    }
    if (tid < NPG) {                      // self-loop diagonal (degree = cnt+1)
      int idx = tid * 208 + tid;
      atomicAdd(&s.adjN[idx >> 3], 1u << ((idx & 7) * 4));
    }
  }

  // ---- GEMM1: H = X @ W — FREE-RUNNING, no barriers, 3-deep x ring ----
  v4f acc[2][4];
  #pragma unroll
  for (int a = 0; a < 2; ++a)
    #pragma unroll
    for (int b = 0; b < 4; ++b)
      acc[a][b] = (v4f){0.f, 0.f, 0.f, 0.f};

  const unsigned short* wl = (const unsigned short*)s.u.wl;
  kt1<0>(x, base, q, mts, nrow, wl, xa[0], acc, lane);
  kt1<1>(x, base, q, mts, nrow, wl, xa[1], acc, lane);
  kt1<2>(x, base, q, mts, nrow, wl, xa[2], acc, lane);
  kt1<3>(x, base, q, mts, nrow, wl, xa[0], acc, lane);
  kt1<4>(x, base, q, mts, nrow, wl, xa[1], acc, lane);
  kt1<5>(x, base, q, mts, nrow, wl, xa[2], acc, lane);
  kt1<6>(x, base, q, mts, nrow, wl, xa[0], acc, lane);
  __syncthreads();    // scatter + cnt complete; all waves done reading W; wl dead

  // ---- dinv table + pad-zero hpTl cols [200,232) + epilogue1 ----
  if (tid < NPG) s.dinv[tid] = rsqrtf((float)(s.cnt[tid] + 1));
  {
    int ch = tid >> 3, grp = tid & 7;
    *(uint2*)&s.u.hpTl[ch * HPITCH + 200 + grp * 4] = (uint2){0u, 0u};
  }
  #pragma unroll
  for (int mi = 0; mi < 2; ++mi) {
    if (mts[mi] >= 0) {
      const int node = mts[mi] * 16 + ml;
      if (node < NPG) {
        const float dv = rsqrtf((float)(s.cnt[node] + 1));   // bitwise == s.dinv[node]
        #pragma unroll
        for (int nt = 0; nt < 4; ++nt) {
          #pragma unroll
          for (int r = 0; r < 4; ++r) {
            const int ch = nt * 16 + q * 4 + r;
            s.u.hpTl[ch * HPITCH + node] = (unsigned short)bf16_rne(dv * acc[mi][nt][r]);
          }
        }
      }
    }
  }
  __syncthreads();

  // ---- GEMM2: AGG = (A+I) @ hp (4-bit counts exact in bf16) ----
  {
    v4f acc2[2][4];
    #pragma unroll
    for (int a = 0; a < 2; ++a)
      #pragma unroll
      for (int b = 0; b < 4; ++b)
        acc2[a][b] = (v4f){0.f, 0.f, 0.f, 0.f};

    for (int kt = 0; kt < 7; ++kt) {
      const int k0 = kt * 32 + q * 8;

      v8s bf[4];
      #pragma unroll
      for (int nt = 0; nt < 4; ++nt)
        bf[nt] = *(const v8s*)&s.u.hpTl[(nt * 16 + ml) * HPITCH + k0];

      #pragma unroll
      for (int mi = 0; mi < 2; ++mi) {
        if (mts[mi] >= 0) {
          const int row = mts[mi] * 16 + ml;
          const int arow = (row < NPG) ? row : 0;     // adjN has 200 rows
          const unsigned dd = s.adjN[arow * NPITCH + (k0 >> 3)];
          v8s af;
          #pragma unroll
          for (int i = 0; i < 8; ++i)
            af[i] = (short)(__float_as_uint((float)((dd >> (4 * i)) & 0xFu)) >> 16);
          #pragma unroll
          for (int nt = 0; nt < 4; ++nt)
            acc2[mi][nt] = __builtin_amdgcn_mfma_f32_16x16x32_bf16(af, bf[nt], acc2[mi][nt], 0, 0, 0);
        }
      }
    }

    // epilogue2: relu(dinv[dst]*agg + cb) -> max-pool
    float cbv[4];
    #pragma unroll
    for (int nt = 0; nt < 4; ++nt) cbv[nt] = cb[nt * 16 + ml];
    float mx[4] = {0.f, 0.f, 0.f, 0.f};
    #pragma unroll
    for (int mi = 0; mi < 2; ++mi) {
      if (mts[mi] >= 0) {
        #pragma unroll
        for (int r = 0; r < 4; ++r) {
          const int row = mts[mi] * 16 + q * 4 + r;
          if (row < NPG) {
            const float dv = s.dinv[row];
            #pragma unroll
            for (int nt = 0; nt < 4; ++nt) {
              float v = fmaxf(fmaf(dv, acc2[mi][nt][r], cbv[nt]), 0.f);
              mx[nt] = fmaxf(mx[nt], v);
            }
          }
        }
      }
    }
    #pragma unroll
    for (int nt = 0; nt < 4; ++nt) {
      mx[nt] = fmaxf(mx[nt], __shfl_xor(mx[nt], 16));
      mx[nt] = fmaxf(mx[nt], __shfl_xor(mx[nt], 32));
    }
    if (q == 0 && (lane >> 5) == 0) {
      #pragma unroll
      for (int nt = 0; nt < 4; ++nt)
        atomicMax(&s.pool[nt * 16 + ml], __float_as_int(mx[nt]));
    }
  }
  __syncthreads();

  // ---- write x_pool and out ----
  if (tid < HID) {
    const float xp = __int_as_float(s.pool[tid]);
    out[NUM_GRAPHS * OUTC + g * HID + tid] = xp;
    float p0 = xp * lw[tid * 2 + 0];
    float p1 = xp * lw[tid * 2 + 1];
    #pragma unroll
    for (int off = 32; off > 0; off >>= 1) {
      p0 += __shfl_down(p0, off);
      p1 += __shfl_down(p1, off);
    }
    if (tid == 0) {
      out[g * OUTC + 0] = p0 + lb[0];
      out[g * OUTC + 1] = p1 + lb[1];
    }
  }
}

// ============ fallback (ws too small): fused kernel, inline W convert ============
struct __align__(16) SmemF {
  unsigned char adj[208 * APITCH];
  unsigned short hpT[HID * HPITCH];
  float dinv[NPG];
  int cnt[NPG];
  int pool[HID];
};

__global__ __launch_bounds__(512, 4)
void gcn_fused_fb(const float* __restrict__ x,
                  const int* __restrict__ ei,
                  const float* __restrict__ cw,
                  const float* __restrict__ cb,
                  const float* __restrict__ lw,
                  const float* __restrict__ lb,
                  float* __restrict__ out,
                  int Etot) {
  __shared__ SmemF s;
  const int g = blockIdx.x;
  const int tid = threadIdx.x;
  const int base = g * NPG;
  const int ebase = g * EPG;
  const int lane = tid & 63;
  const int w = __builtin_amdgcn_readfirstlane(tid >> 6);
  const int ml = tid & 15;
  const int q  = (tid >> 4) & 3;

  {
    uint4* z = (uint4*)&s;
    const uint4 z4 = {0u, 0u, 0u, 0u};
    #pragma unroll
    for (int i = 0; i < 10; ++i) {
      int idx = tid + i * 512;
      if (idx < (208 * APITCH + HID * HPITCH * 2) / 16) z[idx] = z4;
    }
    if (tid < NPG) s.cnt[tid] = 0;
    if (tid < HID) s.pool[tid] = 0;
  }
  __syncthreads();

  int esrc[7], edst[7];
  #pragma unroll
  for (int r = 0; r < 7; ++r) {
    int e = tid + r * 512;
    esrc[r] = -1; edst[r] = 0;
    if (e < EPG) {
      esrc[r] = ei[ebase + e] - base;
      edst[r] = ei[Etot + ebase + e] - base;
      atomicAdd(&s.cnt[edst[r]], 1);
    }
  }
  __syncthreads();

  if (tid < NPG) s.dinv[tid] = rsqrtf((float)(s.cnt[tid] + 1));

  {
    unsigned* adjW = (unsigned*)s.adj;
    #pragma unroll
    for (int r = 0; r < 7; ++r) {
      if (esrc[r] >= 0) {
        int idx = edst[r] * APITCH + esrc[r];
        atomicAdd(&adjW[idx >> 2], 1u << ((idx & 3) * 8));
      }
    }
    if (tid < NPG) {
      int idx = tid * APITCH + tid;
      atomicAdd(&adjW[idx >> 2], 1u << ((idx & 3) * 8));
    }
  }
  __syncthreads();

  {
    int mts[2];
    mts[0] = w;
    mts[1] = (w < 5) ? 8 + w : -1;
    v4f acc[2][4];
    #pragma unroll
    for (int a = 0; a < 2; ++a)
      #pragma unroll
      for (int b = 0; b < 4; ++b)
        acc[a][b] = (v4f){0.f, 0.f, 0.f, 0.f};

    for (int kt = 0; kt < 7; ++kt) {
      const int k0 = kt * 32 + q * 8;
      const bool kok = (k0 < NROIS);
      v8s bhi[4], blo[4];
      #pragma unroll
      for (int nt = 0; nt < 4; ++nt) {
        #pragma unroll
        for (int i = 0; i < 8; ++i) {
          float f = kok ? cw[(k0 + i) * HID + nt * 16 + ml] : 0.f;
          unsigned hb = bf16_rne(f);
          float lo = f - __uint_as_float(hb << 16);
          bhi[nt][i] = (short)hb;
          blo[nt][i] = (short)(__float_as_uint(lo) >> 16);
        }
      }
      #pragma unroll
      for (int mi = 0; mi < 2; ++mi) {
        if (mts[mi] >= 0) {
          const int row = mts[mi] * 16 + ml;
          v8s ahi, alo;
          if (kok && row < NPG) {
            const float* px = x + (size_t)(base + row) * NROIS + k0;
            const float4 f0 = *(const float4*)px;
            const float4 f1 = *(const float4*)(px + 4);
            const float ff[8] = {f0.x, f0.y, f0.z, f0.w, f1.x, f1.y, f1.z, f1.w};
            #pragma unroll
            for (int i = 0; i < 8; ++i) {
              unsigned u = __float_as_uint(ff[i]);
              unsigned hb = u >> 16;
              float lo = ff[i] - __uint_as_float(hb << 16);
              ahi[i] = (short)hb;
              alo[i] = (short)(__float_as_uint(lo) >> 16);
            }
          } else {
            #pragma unroll
            for (int i = 0; i < 8; ++i) { ahi[i] = 0; alo[i] = 0; }
          }
          #pragma unroll
          for (int nt = 0; nt < 4; ++nt) {
            acc[mi][nt] = __builtin_amdgcn_mfma_f32_16x16x32_bf16(ahi, blo[nt], acc[mi][nt], 0, 0, 0);
            acc[mi][nt] = __builtin_amdgcn_mfma_f32_16x16x32_bf16(alo, bhi[nt], acc[mi][nt], 0, 0, 0);
            acc[mi][nt] = __builtin_amdgcn_mfma_f32_16x16x32_bf16(ahi, bhi[nt], acc[mi][nt], 0, 0, 0);
          }
        }
      }
    }
    #pragma unroll
    for (int mi = 0; mi < 2; ++mi) {
      if (mts[mi] >= 0) {
        #pragma unroll
        for (int r = 0; r < 4; ++r) {
          const int row = mts[mi] * 16 + q * 4 + r;
          if (row < NPG) {
            const float dv = s.dinv[row];
            #pragma unroll
            for (int nt = 0; nt < 4; ++nt)
              s.hpT[(nt * 16 + ml) * HPITCH + row] =
                  (unsigned short)bf16_rne(dv * acc[mi][nt][r]);
          }
        }
      }
    }
  }
  __syncthreads();

  {
    int mts[2];
    mts[0] = w;
    mts[1] = (w < 5) ? 8 + w : -1;
    v4f acc2[2][4];
    #pragma unroll
    for (int a = 0; a < 2; ++a)
      #pragma unroll
      for (int b = 0; b < 4; ++b)
        acc2[a][b] = (v4f){0.f, 0.f, 0.f, 0.f};

    for (int kt = 0; kt < 7; ++kt) {
      const int k0 = kt * 32 + q * 8;
      v8s bf[4];
      #pragma unroll
      for (int nt = 0; nt < 4; ++nt)
        bf[nt] = *(const v8s*)&s.hpT[(nt * 16 + ml) * HPITCH + k0];
      #pragma unroll
      for (int mi = 0; mi < 2; ++mi) {
        if (mts[mi] >= 0) {
          const int row = mts[mi] * 16 + ml;
          const uint2 dd = *(const uint2*)&s.adj[row * APITCH + k0];
          v8s af;
          #pragma unroll
          for (int i = 0; i < 4; ++i) {
            af[i]     = (short)(__float_as_uint((float)((dd.x >> (8 * i)) & 0xffu)) >> 16);
            af[i + 4] = (short)(__float_as_uint((float)((dd.y >> (8 * i)) & 0xffu)) >> 16);
          }
          #pragma unroll
          for (int nt = 0; nt < 4; ++nt)
            acc2[mi][nt] = __builtin_amdgcn_mfma_f32_16x16x32_bf16(af, bf[nt], acc2[mi][nt], 0, 0, 0);
        }
      }
    }

    float cbv[4];
    #pragma unroll
    for (int nt = 0; nt < 4; ++nt) cbv[nt] = cb[nt * 16 + ml];
    float mx[4] = {0.f, 0.f, 0.f, 0.f};
    #pragma unroll
    for (int mi = 0; mi < 2; ++mi) {
      if (mts[mi] >= 0) {
        #pragma unroll
        for (int r = 0; r < 4; ++r) {
          const int row = mts[mi] * 16 + q * 4 + r;
          if (row < NPG) {
            const float dv = s.dinv[row];
            #pragma unroll
            for (int nt = 0; nt < 4; ++nt) {
              float v = fmaxf(fmaf(dv, acc2[mi][nt][r], cbv[nt]), 0.f);
              mx[nt] = fmaxf(mx[nt], v);
            }
          }
        }
      }
    }
    #pragma unroll
    for (int nt = 0; nt < 4; ++nt) {
      mx[nt] = fmaxf(mx[nt], __shfl_xor(mx[nt], 16));
      mx[nt] = fmaxf(mx[nt], __shfl_xor(mx[nt], 32));
    }
    if (q == 0 && (lane >> 5) == 0) {
      #pragma unroll
      for (int nt = 0; nt < 4; ++nt)
        atomicMax(&s.pool[nt * 16 + ml], __float_as_int(mx[nt]));
    }
  }
  __syncthreads();

  if (tid < HID) {
    const float xp = __int_as_float(s.pool[tid]);
    out[NUM_GRAPHS * OUTC + g * HID + tid] = xp;
    float p0 = xp * lw[tid * 2 + 0];
    float p1 = xp * lw[tid * 2 + 1];
    #pragma unroll
    for (int off = 32; off > 0; off >>= 1) {
      p0 += __shfl_down(p0, off);
      p1 += __shfl_down(p1, off);
    }
    if (tid == 0) {
      out[g * OUTC + 0] = p0 + lb[0];
      out[g * OUTC + 1] = p1 + lb[1];
    }
  }
}

extern "C" void kernel_launch(void* const* d_in, const int* in_sizes, int n_in,
                              void* d_out, int out_size, void* d_ws, size_t ws_size,
                              hipStream_t stream) {
  const float* x  = (const float*)d_in[0];
  const int*   ei = (const int*)d_in[1];
  // d_in[2] = batch (node/200 by construction; unused)
  const float* cw = (const float*)d_in[3];
  const float* cb = (const float*)d_in[4];
  const float* lw = (const float*)d_in[5];
  const float* lb = (const float*)d_in[6];
  const int Etot = in_sizes[1] / 2;

  if (ws_size >= WS_NEEDED) {
    unsigned short* wimg = (unsigned short*)d_ws;
    prep_wimg<<<(WIMG_ELEMS + 255) / 256, 256, 0, stream>>>(cw, wimg);
    gcn_fused10<<<NUM_GRAPHS, 512, 0, stream>>>(x, ei, wimg, cb, lw, lb,
                                                (float*)d_out, Etot);
  } else {
    gcn_fused_fb<<<NUM_GRAPHS, 512, 0, stream>>>(x, ei, cw, cb, lw, lb,
                                                 (float*)d_out, Etot);
  }
}

// Round 8
// 144.258 us; speedup vs baseline: 1.0293x; 1.0293x over previous
//
#include <hip/hip_runtime.h>

#define NUM_GRAPHS 512
#define NPG 200      // nodes per graph
#define EPG 3200     // edges per graph
#define NROIS 200    // input feature dim
#define HID 64
#define OUTC 2
#define APITCH 232   // adjacency row pitch (bytes) = 58 dw
#define HPITCH 232   // hpTl row pitch (elements); 464 B = 29*16 -> b128-aligned rows
#define WIMG_ELEMS (7 * 4 * 2 * 64 * 8)   // 28672 ushorts (W hi/lo frag image)
#define WS_NEEDED ((size_t)WIMG_ELEMS * 2)

typedef short v8s __attribute__((ext_vector_type(8)));
typedef float v4f __attribute__((ext_vector_type(4)));

__device__ __forceinline__ unsigned bf16_rne(float f) {
  unsigned u = __float_as_uint(f);
  return (u + 0x7fffu + ((u >> 16) & 1u)) >> 16;
}

// ============ prep: W -> bf16 hi/lo fragment-order image ============
__global__ void prep_wimg(const float* __restrict__ cw, unsigned short* __restrict__ wimg) {
  int idx = blockIdx.x * 256 + threadIdx.x;
  if (idx >= WIMG_ELEMS) return;
  int i    = idx & 7;
  int lane = (idx >> 3) & 63;
  int hl   = (idx >> 9) & 1;
  int nt   = (idx >> 10) & 3;
  int kt   = idx >> 12;
  int k  = kt * 32 + (lane >> 4) * 8 + i;
  int ch = nt * 16 + (lane & 15);
  float f = (k < NROIS) ? cw[k * HID + ch] : 0.f;
  unsigned hi = bf16_rne(f);
  float lo = f - __uint_as_float(hi << 16);
  wimg[idx] = hl ? (unsigned short)(__float_as_uint(lo) >> 16) : (unsigned short)hi;
}

// ============ fused kernel v8 (best measured: 145.2 us total) ============
// v5 structure + W-tile staged in LDS once per block per kt (global_load_lds,
// double-buffered, 8KB/tile) instead of per-wave L2 loads: block wimg traffic
// 448KB -> 57KB (chip-wide 229MB -> 29MB per iteration). Costs one syncthreads
// per kt. Numerics identical to v5.
// LDS: 48256 (adj) + 29696 (hpTl | wbuf 16KB) + 800 + 800 + 256
//    = 79808 B -> 2 blocks/CU (16 waves).
struct __align__(16) Smem2 {
  unsigned char adj[208 * APITCH];        // (A+I) counts as bytes
  union {
    unsigned short hpTl[HID * HPITCH];    // bf16 dinv[src]*h[src][ch] (post-GEMM1)
    unsigned int wbuf[2][2048];           // 2 x 8KB W-tile double buffer (GEMM1)
  } u;
  int cnt[NPG];                           // in-degree (edges only; +1 for self-loop)
  float dinv[NPG];
  int pool[HID];
};

__device__ __forceinline__ v8s tobf16(const float4& a, const float4& b) {
  v8s r;
  r[0] = (short)bf16_rne(a.x); r[1] = (short)bf16_rne(a.y);
  r[2] = (short)bf16_rne(a.z); r[3] = (short)bf16_rne(a.w);
  r[4] = (short)bf16_rne(b.x); r[5] = (short)bf16_rne(b.y);
  r[6] = (short)bf16_rne(b.z); r[7] = (short)bf16_rne(b.w);
  return r;
}

// stage W tile kt (8KB) into wbuf[buf]: each thread DMAs one 16B chunk.
// LDS dest is wave-uniform base (+lane*16 by HW); global src is per-lane.
__device__ __forceinline__ void stageW(Smem2& s, const unsigned short* __restrict__ wimg,
                                       int kt, int buf, int w, int lane) {
  const char* gp = (const char*)wimg + (size_t)kt * 8192 + (size_t)(w * 64 + lane) * 16;
  unsigned char* lp = (unsigned char*)&s.u.wbuf[buf][0] + w * 1024;
  __builtin_amdgcn_global_load_lds(
      (const __attribute__((address_space(1))) unsigned int*)gp,
      (__attribute__((address_space(3))) unsigned int*)lp, 16, 0, 0);
}

// load the wave's x fragment floats for K-tile kt: lane (mi) reads 8 consecutive
// floats x[node][kt*32 + q*8 .. +8).  kt=6,q>=1 would run past col 200 -> zero-fill.
__device__ __forceinline__ void xfetch(const float* __restrict__ x, int base,
                                       int kt, int q, const int* mts, const int* nrow,
                                       float4 xa[2][2]) {
  const int k0 = kt * 32 + q * 8;
  const bool ok = (k0 + 8 <= NROIS);
  #pragma unroll
  for (int mi = 0; mi < 2; ++mi) {
    if (mts[mi] >= 0) {
      if (ok) {
        const float* px = x + (size_t)(base + nrow[mi]) * NROIS + k0;
        xa[mi][0] = *(const float4*)px;
        xa[mi][1] = *(const float4*)(px + 4);
      } else {
        xa[mi][0] = make_float4(0.f, 0.f, 0.f, 0.f);
        xa[mi][1] = make_float4(0.f, 0.f, 0.f, 0.f);
      }
    }
  }
}

__global__ __launch_bounds__(512, 4)
void gcn_fused8(const float* __restrict__ x,
                const int* __restrict__ ei,
                const unsigned short* __restrict__ wimg,
                const float* __restrict__ cb,
                const float* __restrict__ lw,
                const float* __restrict__ lb,
                float* __restrict__ out,
                int Etot) {
  __shared__ Smem2 s;
  const int g = blockIdx.x;
  const int tid = threadIdx.x;
  const int base = g * NPG;
  const int ebase = g * EPG;
  const int lane = tid & 63;
  const int w = __builtin_amdgcn_readfirstlane(tid >> 6);  // 0..7
  const int ml = tid & 15;
  const int q  = (tid >> 4) & 3;

  int mts[2];
  mts[0] = w;
  mts[1] = (w < 5) ? 8 + w : -1;
  int nrow[2];                       // clamped row index for x loads (junk discarded)
  #pragma unroll
  for (int mi = 0; mi < 2; ++mi) {
    int node = mts[mi] * 16 + ml;
    nrow[mi] = (node < NPG) ? node : 0;
  }

  // ---- startup: issue edge loads + x-tile0 + W-tile0 DMA; zero adj/cnt/pool ----
  int esrc[7], edst[7];
  #pragma unroll
  for (int r = 0; r < 7; ++r) {
    int e = tid + r * 512;
    esrc[r] = -1; edst[r] = 0;
    if (e < EPG) {
      esrc[r] = ei[ebase + e] - base;
      edst[r] = ei[Etot + ebase + e] - base;
    }
  }
  float4 xa[2][2];
  xfetch(x, base, 0, q, mts, nrow, xa);
  stageW(s, wimg, 0, 0, w, lane);           // W[0] DMA; completed by the barrier below
  {
    uint4* z = (uint4*)s.adj;
    const uint4 z4 = {0u, 0u, 0u, 0u};
    #pragma unroll
    for (int i = 0; i < 6; ++i) {
      int idx = tid + i * 512;
      if (idx < (208 * APITCH) / 16) z[idx] = z4;
    }
    if (tid < NPG) s.cnt[tid] = 0;
    if (tid < HID) s.pool[tid] = 0;   // relu >= 0 -> 0 is identity for max
  }
  __syncthreads();   // zeroes visible; W[0]/x[0] drained (full vmcnt drain)

  // ---- scatter (A+I) counts + in-degree (fire-and-forget ds atomics; they drain
  //      at the first in-loop barrier, long before adj/cnt are read) ----
  {
    unsigned* adjW = (unsigned*)s.adj;
    #pragma unroll
    for (int r = 0; r < 7; ++r) {
      if (esrc[r] >= 0) {
        int idx = edst[r] * APITCH + esrc[r];
        atomicAdd(&adjW[idx >> 2], 1u << ((idx & 3) * 8));
        atomicAdd(&s.cnt[edst[r]], 1);
      }
    }
    if (tid < NPG) {                      // self-loop diagonal (degree handled as cnt+1)
      int idx = tid * APITCH + tid;
      atomicAdd(&adjW[idx >> 2], 1u << ((idx & 3) * 8));
    }
  }

  // ---- GEMM1: H = X @ W  (x direct-from-global; W from LDS double buffer) ----
  v4f acc[2][4];
  #pragma unroll
  for (int a = 0; a < 2; ++a)
    #pragma unroll
    for (int b = 0; b < 4; ++b)
      acc[a][b] = (v4f){0.f, 0.f, 0.f, 0.f};

  for (int kt = 0; kt < 7; ++kt) {
    const int cur = kt & 1;
    // DMA next W tile into the other buffer (other buf's readers passed a barrier)
    if (kt < 6) stageW(s, wimg, kt + 1, cur ^ 1, w, lane);
    // convert current x fragments (loads drained at previous barrier)
    v8s xh2[2];
    #pragma unroll
    for (int mi = 0; mi < 2; ++mi)
      if (mts[mi] >= 0) xh2[mi] = tobf16(xa[mi][0], xa[mi][1]);
    if (kt < 6) xfetch(x, base, kt + 1, q, mts, nrow, xa);   // in flight this iter

    // read this kt's W fragments from LDS (contiguous 1KB per fragment id)
    const unsigned short* wb = (const unsigned short*)&s.u.wbuf[cur][0];
    v8s whi[4], wlo[4];
    #pragma unroll
    for (int nt = 0; nt < 4; ++nt) {
      whi[nt] = *(const v8s*)(wb + (size_t)((nt * 2 + 0) * 64 + lane) * 8);
      wlo[nt] = *(const v8s*)(wb + (size_t)((nt * 2 + 1) * 64 + lane) * 8);
    }
    #pragma unroll
    for (int mi = 0; mi < 2; ++mi) {
      if (mts[mi] >= 0) {
        #pragma unroll
        for (int nt = 0; nt < 4; ++nt) {
          acc[mi][nt] = __builtin_amdgcn_mfma_f32_16x16x32_bf16(wlo[nt], xh2[mi], acc[mi][nt], 0, 0, 0);
          acc[mi][nt] = __builtin_amdgcn_mfma_f32_16x16x32_bf16(whi[nt], xh2[mi], acc[mi][nt], 0, 0, 0);
        }
      }
    }
    __syncthreads();   // W[kt+1] DMA + x[kt+1] complete; wbuf swap safe
  }

  // ---- dinv table (for epilogue2) + pad-zero hpTl cols [200,232) + epilogue1 ----
  if (tid < NPG) s.dinv[tid] = rsqrtf((float)(s.cnt[tid] + 1));
  {
    int ch = tid >> 3, grp = tid & 7;
    *(uint2*)&s.u.hpTl[ch * HPITCH + 200 + grp * 4] = (uint2){0u, 0u};
  }
  #pragma unroll
  for (int mi = 0; mi < 2; ++mi) {
    if (mts[mi] >= 0) {
      const int node = mts[mi] * 16 + ml;
      if (node < NPG) {
        const float dv = rsqrtf((float)(s.cnt[node] + 1));   // bitwise == s.dinv[node]
        #pragma unroll
        for (int nt = 0; nt < 4; ++nt) {
          #pragma unroll
          for (int r = 0; r < 4; ++r) {
            const int ch = nt * 16 + q * 4 + r;
            s.u.hpTl[ch * HPITCH + node] = (unsigned short)bf16_rne(dv * acc[mi][nt][r]);
          }
        }
      }
    }
  }
  __syncthreads();

  // ---- GEMM2: AGG = (A+I) @ hp (counts exact in bf16) ----
  {
    v4f acc2[2][4];
    #pragma unroll
    for (int a = 0; a < 2; ++a)
      #pragma unroll
      for (int b = 0; b < 4; ++b)
        acc2[a][b] = (v4f){0.f, 0.f, 0.f, 0.f};

    for (int kt = 0; kt < 7; ++kt) {
      const int k0 = kt * 32 + q * 8;

      v8s bf[4];
      #pragma unroll
      for (int nt = 0; nt < 4; ++nt)
        bf[nt] = *(const v8s*)&s.u.hpTl[(nt * 16 + ml) * HPITCH + k0];

      #pragma unroll
      for (int mi = 0; mi < 2; ++mi) {
        if (mts[mi] >= 0) {
          const int row = mts[mi] * 16 + ml;
          const uint2 dd = *(const uint2*)&s.adj[row * APITCH + k0];
          v8s af;
          #pragma unroll
          for (int i = 0; i < 4; ++i) {
            af[i]     = (short)(__float_as_uint((float)((dd.x >> (8 * i)) & 0xffu)) >> 16);
            af[i + 4] = (short)(__float_as_uint((float)((dd.y >> (8 * i)) & 0xffu)) >> 16);
          }
          #pragma unroll
          for (int nt = 0; nt < 4; ++nt)
            acc2[mi][nt] = __builtin_amdgcn_mfma_f32_16x16x32_bf16(af, bf[nt], acc2[mi][nt], 0, 0, 0);
        }
      }
    }

    // epilogue2: relu(dinv[dst]*agg + cb) -> max-pool
    float cbv[4];
    #pragma unroll
    for (int nt = 0; nt < 4; ++nt) cbv[nt] = cb[nt * 16 + ml];
    float mx[4] = {0.f, 0.f, 0.f, 0.f};
    #pragma unroll
    for (int mi = 0; mi < 2; ++mi) {
      if (mts[mi] >= 0) {
        #pragma unroll
        for (int r = 0; r < 4; ++r) {
          const int row = mts[mi] * 16 + q * 4 + r;
          if (row < NPG) {
            const float dv = s.dinv[row];
            #pragma unroll
            for (int nt = 0; nt < 4; ++nt) {
              float v = fmaxf(fmaf(dv, acc2[mi][nt][r], cbv[nt]), 0.f);
              mx[nt] = fmaxf(mx[nt], v);
            }
          }
        }
      }
    }
    #pragma unroll
    for (int nt = 0; nt < 4; ++nt) {
      mx[nt] = fmaxf(mx[nt], __shfl_xor(mx[nt], 16));
      mx[nt] = fmaxf(mx[nt], __shfl_xor(mx[nt], 32));
    }
    if (q == 0 && (lane >> 5) == 0) {
      #pragma unroll
      for (int nt = 0; nt < 4; ++nt)
        atomicMax(&s.pool[nt * 16 + ml], __float_as_int(mx[nt]));
    }
  }
  __syncthreads();

  // ---- write x_pool and out ----
  if (tid < HID) {
    const float xp = __int_as_float(s.pool[tid]);
    out[NUM_GRAPHS * OUTC + g * HID + tid] = xp;
    float p0 = xp * lw[tid * 2 + 0];
    float p1 = xp * lw[tid * 2 + 1];
    #pragma unroll
    for (int off = 32; off > 0; off >>= 1) {
      p0 += __shfl_down(p0, off);
      p1 += __shfl_down(p1, off);
    }
    if (tid == 0) {
      out[g * OUTC + 0] = p0 + lb[0];
      out[g * OUTC + 1] = p1 + lb[1];
    }
  }
}

// ============ fallback (ws too small): fused kernel, inline W convert ============
struct __align__(16) SmemF {
  unsigned char adj[208 * APITCH];
  unsigned short hpT[HID * HPITCH];
  float dinv[NPG];
  int cnt[NPG];
  int pool[HID];
};

__global__ __launch_bounds__(512, 4)
void gcn_fused_fb(const float* __restrict__ x,
                  const int* __restrict__ ei,
                  const float* __restrict__ cw,
                  const float* __restrict__ cb,
                  const float* __restrict__ lw,
                  const float* __restrict__ lb,
                  float* __restrict__ out,
                  int Etot) {
  __shared__ SmemF s;
  const int g = blockIdx.x;
  const int tid = threadIdx.x;
  const int base = g * NPG;
  const int ebase = g * EPG;
  const int lane = tid & 63;
  const int w = __builtin_amdgcn_readfirstlane(tid >> 6);
  const int ml = tid & 15;
  const int q  = (tid >> 4) & 3;

  {
    uint4* z = (uint4*)&s;
    const uint4 z4 = {0u, 0u, 0u, 0u};
    #pragma unroll
    for (int i = 0; i < 10; ++i) {
      int idx = tid + i * 512;
      if (idx < (208 * APITCH + HID * HPITCH * 2) / 16) z[idx] = z4;
    }
    if (tid < NPG) s.cnt[tid] = 0;
    if (tid < HID) s.pool[tid] = 0;
  }
  __syncthreads();

  int esrc[7], edst[7];
  #pragma unroll
  for (int r = 0; r < 7; ++r) {
    int e = tid + r * 512;
    esrc[r] = -1; edst[r] = 0;
    if (e < EPG) {
      esrc[r] = ei[ebase + e] - base;
      edst[r] = ei[Etot + ebase + e] - base;
      atomicAdd(&s.cnt[edst[r]], 1);
    }
  }
  __syncthreads();

  if (tid < NPG) s.dinv[tid] = rsqrtf((float)(s.cnt[tid] + 1));

  {
    unsigned* adjW = (unsigned*)s.adj;
    #pragma unroll
    for (int r = 0; r < 7; ++r) {
      if (esrc[r] >= 0) {
        int idx = edst[r] * APITCH + esrc[r];
        atomicAdd(&adjW[idx >> 2], 1u << ((idx & 3) * 8));
      }
    }
    if (tid < NPG) {
      int idx = tid * APITCH + tid;
      atomicAdd(&adjW[idx >> 2], 1u << ((idx & 3) * 8));
    }
  }
  __syncthreads();

  {
    int mts[2];
    mts[0] = w;
    mts[1] = (w < 5) ? 8 + w : -1;
    v4f acc[2][4];
    #pragma unroll
    for (int a = 0; a < 2; ++a)
      #pragma unroll
      for (int b = 0; b < 4; ++b)
        acc[a][b] = (v4f){0.f, 0.f, 0.f, 0.f};

    for (int kt = 0; kt < 7; ++kt) {
      const int k0 = kt * 32 + q * 8;
      const bool kok = (k0 < NROIS);
      v8s bhi[4], blo[4];
      #pragma unroll
      for (int nt = 0; nt < 4; ++nt) {
        #pragma unroll
        for (int i = 0; i < 8; ++i) {
          float f = kok ? cw[(k0 + i) * HID + nt * 16 + ml] : 0.f;
          unsigned hb = bf16_rne(f);
          float lo = f - __uint_as_float(hb << 16);
          bhi[nt][i] = (short)hb;
          blo[nt][i] = (short)(__float_as_uint(lo) >> 16);
        }
      }
      #pragma unroll
      for (int mi = 0; mi < 2; ++mi) {
        if (mts[mi] >= 0) {
          const int row = mts[mi] * 16 + ml;
          v8s ahi, alo;
          if (kok && row < NPG) {
            const float* px = x + (size_t)(base + row) * NROIS + k0;
            const float4 f0 = *(const float4*)px;
            const float4 f1 = *(const float4*)(px + 4);
            const float ff[8] = {f0.x, f0.y, f0.z, f0.w, f1.x, f1.y, f1.z, f1.w};
            #pragma unroll
            for (int i = 0; i < 8; ++i) {
              unsigned u = __float_as_uint(ff[i]);
              unsigned hb = u >> 16;
              float lo = ff[i] - __uint_as_float(hb << 16);
              ahi[i] = (short)hb;
              alo[i] = (short)(__float_as_uint(lo) >> 16);
            }
          } else {
            #pragma unroll
            for (int i = 0; i < 8; ++i) { ahi[i] = 0; alo[i] = 0; }
          }
          #pragma unroll
          for (int nt = 0; nt < 4; ++nt) {
            acc[mi][nt] = __builtin_amdgcn_mfma_f32_16x16x32_bf16(ahi, blo[nt], acc[mi][nt], 0, 0, 0);
            acc[mi][nt] = __builtin_amdgcn_mfma_f32_16x16x32_bf16(alo, bhi[nt], acc[mi][nt], 0, 0, 0);
            acc[mi][nt] = __builtin_amdgcn_mfma_f32_16x16x32_bf16(ahi, bhi[nt], acc[mi][nt], 0, 0, 0);
          }
        }
      }
    }
    #pragma unroll
    for (int mi = 0; mi < 2; ++mi) {
      if (mts[mi] >= 0) {
        #pragma unroll
        for (int r = 0; r < 4; ++r) {
          const int row = mts[mi] * 16 + q * 4 + r;
          if (row < NPG) {
            const float dv = s.dinv[row];
            #pragma unroll
            for (int nt = 0; nt < 4; ++nt)
              s.hpT[(nt * 16 + ml) * HPITCH + row] =
                  (unsigned short)bf16_rne(dv * acc[mi][nt][r]);
          }
        }
      }
    }
  }
  __syncthreads();

  {
    int mts[2];
    mts[0] = w;
    mts[1] = (w < 5) ? 8 + w : -1;
    v4f acc2[2][4];
    #pragma unroll
    for (int a = 0; a < 2; ++a)
      #pragma unroll
      for (int b = 0; b < 4; ++b)
        acc2[a][b] = (v4f){0.f, 0.f, 0.f, 0.f};

    for (int kt = 0; kt < 7; ++kt) {
      const int k0 = kt * 32 + q * 8;
      v8s bf[4];
      #pragma unroll
      for (int nt = 0; nt < 4; ++nt)
        bf[nt] = *(const v8s*)&s.hpT[(nt * 16 + ml) * HPITCH + k0];
      #pragma unroll
      for (int mi = 0; mi < 2; ++mi) {
        if (mts[mi] >= 0) {
          const int row = mts[mi] * 16 + ml;
          const uint2 dd = *(const uint2*)&s.adj[row * APITCH + k0];
          v8s af;
          #pragma unroll
          for (int i = 0; i < 4; ++i) {
            af[i]     = (short)(__float_as_uint((float)((dd.x >> (8 * i)) & 0xffu)) >> 16);
            af[i + 4] = (short)(__float_as_uint((float)((dd.y >> (8 * i)) & 0xffu)) >> 16);
          }
          #pragma unroll
          for (int nt = 0; nt < 4; ++nt)
            acc2[mi][nt] = __builtin_amdgcn_mfma_f32_16x16x32_bf16(af, bf[nt], acc2[mi][nt], 0, 0, 0);
        }
      }
    }

    float cbv[4];
    #pragma unroll
    for (int nt = 0; nt < 4; ++nt) cbv[nt] = cb[nt * 16 + ml];
    float mx[4] = {0.f, 0.f, 0.f, 0.f};
    #pragma unroll
    for (int mi = 0; mi < 2; ++mi) {
      if (mts[mi] >= 0) {
        #pragma unroll
        for (int r = 0; r < 4; ++r) {
          const int row = mts[mi] * 16 + q * 4 + r;
          if (row < NPG) {
            const float dv = s.dinv[row];
            #pragma unroll
            for (int nt = 0; nt < 4; ++nt) {
              float v = fmaxf(fmaf(dv, acc2[mi][nt][r], cbv[nt]), 0.f);
              mx[nt] = fmaxf(mx[nt], v);
            }
          }
        }
      }
    }
    #pragma unroll
    for (int nt = 0; nt < 4; ++nt) {
      mx[nt] = fmaxf(mx[nt], __shfl_xor(mx[nt], 16));
      mx[nt] = fmaxf(mx[nt], __shfl_xor(mx[nt], 32));
    }
    if (q == 0 && (lane >> 5) == 0) {
      #pragma unroll
      for (int nt = 0; nt < 4; ++nt)
        atomicMax(&s.pool[nt * 16 + ml], __float_as_int(mx[nt]));
    }
  }
  __syncthreads();

  if (tid < HID) {
    const float xp = __int_as_float(s.pool[tid]);
    out[NUM_GRAPHS * OUTC + g * HID + tid] = xp;
    float p0 = xp * lw[tid * 2 + 0];
    float p1 = xp * lw[tid * 2 + 1];
    #pragma unroll
    for (int off = 32; off > 0; off >>= 1) {
      p0 += __shfl_down(p0, off);
      p1 += __shfl_down(p1, off);
    }
    if (tid == 0) {
      out[g * OUTC + 0] = p0 + lb[0];
      out[g * OUTC + 1] = p1 + lb[1];
    }
  }
}

extern "C" void kernel_launch(void* const* d_in, const int* in_sizes, int n_in,
                              void* d_out, int out_size, void* d_ws, size_t ws_size,
                              hipStream_t stream) {
  const float* x  = (const float*)d_in[0];
  const int*   ei = (const int*)d_in[1];
  // d_in[2] = batch (node/200 by construction; unused)
  const float* cw = (const float*)d_in[3];
  const float* cb = (const float*)d_in[4];
  const float* lw = (const float*)d_in[5];
  const float* lb = (const float*)d_in[6];
  const int Etot = in_sizes[1] / 2;

  if (ws_size >= WS_NEEDED) {
    unsigned short* wimg = (unsigned short*)d_ws;
    prep_wimg<<<(WIMG_ELEMS + 255) / 256, 256, 0, stream>>>(cw, wimg);
    gcn_fused8<<<NUM_GRAPHS, 512, 0, stream>>>(x, ei, wimg, cb, lw, lb,
                                               (float*)d_out, Etot);
  } else {
    gcn_fused_fb<<<NUM_GRAPHS, 512, 0, stream>>>(x, ei, cw, cb, lw, lb,
                                                 (float*)d_out, Etot);
  }
}